// Round 12
// baseline (148.509 us; speedup 1.0000x reference)
//
#include <hip/hip_runtime.h>

#define BB 4
#define SS 4096
#define DDIM 1024
#define KDIM 64
#define NCHUNK 64          // SS / CHUNK
#define TCHUNK 256         // BB * NCHUNK
#define MROWS 16384        // BB * SS

typedef short short8v __attribute__((ext_vector_type(8)));
typedef float f32x4 __attribute__((ext_vector_type(4)));
#define MFMA16 __builtin_amdgcn_mfma_f32_16x16x32_bf16

#define GLDS16(gp, lp) __builtin_amdgcn_global_load_lds( \
    (const __attribute__((address_space(1))) unsigned int*)(gp), \
    (__attribute__((address_space(3))) unsigned int*)(lp), 16, 0, 0)

__device__ __forceinline__ ushort f2bf(float f) {
    uint u = __float_as_uint(f);
    u += 0x7FFFu + ((u >> 16) & 1u);
    return (ushort)(u >> 16);
}

__device__ __forceinline__ uint cvtpk(float lo, float hi) {
    uint r;
    asm("v_cvt_pk_bf16_f32 %0, %1, %2" : "=v"(r) : "v"(lo), "v"(hi));
    return r;
}

// ---------------- Kernel 0: weight conversion + fragment packing ----------------
__global__ __launch_bounds__(256) void k_wconv(
    const float* __restrict__ Wq, const float* __restrict__ Wk,
    const float* __restrict__ Wv, const float* __restrict__ Wo,
    ushort* __restrict__ Whf, ushort* __restrict__ Wof)
{
    const int b = blockIdx.x, t = threadIdx.x;
    const int ks = t >> 7;            // 0..1
    const int l = (t >> 1) & 63;      // lane
    const int half = t & 1;           // low/high 4 elems
    if (b < 192) {
        const int s = b / 12, cf = b % 12;
        const int grow = cf * 16 + (l & 15);
        const int gcol = s * 64 + ks * 32 + ((l >> 4) & 3) * 8 + half * 4;
        const float* src = (grow < 64) ? (Wq + (size_t)grow * DDIM)
                         : (grow < 128) ? (Wk + (size_t)(grow - 64) * DDIM)
                                        : (Wv + (size_t)(grow - 128) * DDIM);
        float4 v = *(const float4*)&src[gcol];
        ushort* dst = &Whf[(size_t)(((s * 12 + cf) * 2 + ks) * 64 + l) * 8 + half * 4];
        dst[0] = f2bf(v.x); dst[1] = f2bf(v.y); dst[2] = f2bf(v.z); dst[3] = f2bf(v.w);
    } else {
        const int cf = b - 192;           // 0..63
        const int d = cf * 16 + (l & 15);
        const int kc = ks * 32 + ((l >> 4) & 3) * 8 + half * 4;
        float4 v = *(const float4*)&Wo[(size_t)d * KDIM + kc];
        ushort* dst = &Wof[(size_t)((cf * 2 + ks) * 64 + l) * 8 + half * 4];
        dst[0] = f2bf(v.x); dst[1] = f2bf(v.y); dst[2] = f2bf(v.z); dst[3] = f2bf(v.w);
    }
}

// ---------------- Kernel 1: fused QKV projection v7 (m97-style) ----------------
// BM=64 (= chunk), BN=192, BK=64; grid 256, 512 thr = 8 waves (rw = w>>2, cw = w&3),
// wave tile 32x48 (acc[2][3]). x reg-staged -> bf16 frags (cvt at stage time);
// W via 24 shared global_load_lds per step; double-buffered; 1 barrier/step;
// stage(next) issued BEFORE compute(cur).
#define EBP 216
__global__ __launch_bounds__(512, 2) void k_proj(
    const float* __restrict__ x, const ushort* __restrict__ Whf,
    ushort* __restrict__ Qf, ushort* __restrict__ Kff,
    ushort* __restrict__ KfT, ushort* __restrict__ VT)
{
    __shared__ ushort lds[2][16384];   // per buf: A frags 8*512 | B frags 24*512 (32 KB)
    const int t = threadIdx.x;
    const int w = t >> 6, l = t & 63;
    const int rw = w >> 2, cw = w & 3;
    const int g = blockIdx.x;
    const int row0 = g * 64;
    const int lq = l >> 4;

    // x-stage geometry: thread t -> row sr=t>>3, cols sc=(t&7)*8 of the 64-col slice
    const int sr = t >> 3;
    const int sc = (t & 7) * 8;
    const int s_slot = (((sr >> 4) * 2 + (sc >> 5)) * 64
                        + ((sr & 15) | (((sc >> 3) & 3) << 4))) * 8;
    const float* xbase = &x[(size_t)(row0 + sr) * DDIM + sc];

    auto stage = [&](int s, int buf) {
#pragma unroll
        for (int ii = 0; ii < 3; ++ii) {
            const int f = w * 3 + ii;
            const ushort* gp = &Whf[(size_t)(s * 24 + f) * 512 + l * 8];
            GLDS16(gp, &lds[buf][(8 + f) * 512]);
        }
        const float* p = xbase + s * 64;
        float4 u0 = *(const float4*)p;
        float4 u1 = *(const float4*)(p + 4);
        uint4 pk;
        pk.x = cvtpk(u0.x, u0.y); pk.y = cvtpk(u0.z, u0.w);
        pk.z = cvtpk(u1.x, u1.y); pk.w = cvtpk(u1.z, u1.w);
        *(uint4*)&lds[buf][s_slot] = pk;
    };

    f32x4 acc[2][3];
#pragma unroll
    for (int j = 0; j < 2; ++j)
#pragma unroll
        for (int c = 0; c < 3; ++c) acc[j][c] = (f32x4){0.f, 0.f, 0.f, 0.f};

    auto compute = [&](int buf) {
#pragma unroll
        for (int ks = 0; ks < 2; ++ks) {
            short8v a0 = *(const short8v*)&lds[buf][(((rw * 2 + 0) * 2 + ks) * 64 + l) * 8];
            short8v a1 = *(const short8v*)&lds[buf][(((rw * 2 + 1) * 2 + ks) * 64 + l) * 8];
#pragma unroll
            for (int c = 0; c < 3; ++c) {
                short8v b = *(const short8v*)&lds[buf][(8 + ((cw * 3 + c) * 2 + ks)) * 512 + l * 8];
                acc[0][c] = MFMA16(a0, b, acc[0][c], 0, 0, 0);
                acc[1][c] = MFMA16(a1, b, acc[1][c], 0, 0, 0);
            }
        }
    };

    stage(0, 0);
    __syncthreads();
    for (int s = 0; s < 16; ++s) {
        const int cur = s & 1;
        if (s < 15) stage(s + 1, cur ^ 1);   // loads in flight during compute
        compute(cur);
        __syncthreads();                      // drains glds; next buf ready
    }

    // ---- epilogue: C-frags -> eb[64][EBP] (elu+1 on cols<128) ----
    ushort* eb = &lds[0][0];
#pragma unroll
    for (int j = 0; j < 2; ++j)
#pragma unroll
        for (int c = 0; c < 3; ++c) {
            const int col = (cw * 3 + c) * 16 + (l & 15);
#pragma unroll
            for (int q = 0; q < 4; ++q) {
                const int row = rw * 32 + j * 16 + lq * 4 + q;
                float v = acc[j][c][q];
                if (col < 128) v = (v > 0.f) ? v + 1.f : __expf(v);  // elu+1
                eb[row * EBP + col] = f2bf(v);
            }
        }
    __syncthreads();

    // ---- Qf/Kff row-frag stores (8 waves: which, rh, rfm) ----
    {
        const int which = w >> 2, rh = (w >> 1) & 1, rfm = w & 1;
#pragma unroll
        for (int ks = 0; ks < 2; ++ks) {
            const int r = rh * 32 + rfm * 16 + (l & 15);
            const int c0 = ks * 32 + ((l >> 4) & 3) * 8 + (which ? 64 : 0);
            short8v v8 = *(const short8v*)&eb[r * EBP + c0];
            const size_t fo = ((size_t)((g * 2 + rh) * 4 + rfm * 2 + ks)) * 512 + l * 8;
            if (which == 0) *(short8v*)&Qf[fo] = v8;
            else            *(short8v*)&Kff[fo] = v8;
        }
    }
    // ---- KfT/VT T-frag stores (8 waves: which, f; js loop) ----
    {
        const int which = w >> 2, f = w & 3;
#pragma unroll
        for (int js = 0; js < 2; ++js) {
            const int col = (which ? 128 : 64) + f * 16 + (l & 15);
            const int jb = js * 32 + ((l >> 4) & 3) * 8;
            short8v tv;
#pragma unroll
            for (int e = 0; e < 8; ++e) tv[e] = (short)eb[(jb + e) * EBP + col];
            const size_t fo = ((size_t)(g * 8 + f * 2 + js)) * 512 + l * 8;
            if (which == 0) *(short8v*)&KfT[fo] = tv;
            else            *(short8v*)&VT[fo]  = tv;
        }
    }
}

// ---------------- PROBE A: staging phase only, amplified x4 ----------------
__global__ __launch_bounds__(512, 2) void k_probe_stage(
    const float* __restrict__ x, const ushort* __restrict__ Whf,
    float* __restrict__ scratch)
{
    __shared__ ushort lds[2][16384];
    const int t = threadIdx.x;
    const int w = t >> 6, l = t & 63;
    const int g = blockIdx.x;
    const int row0 = g * 64;
    const int sr = t >> 3;
    const int sc = (t & 7) * 8;
    const int s_slot = (((sr >> 4) * 2 + (sc >> 5)) * 64
                        + ((sr & 15) | (((sc >> 3) & 3) << 4))) * 8;
    const float* xbase = &x[(size_t)(row0 + sr) * DDIM + sc];

    for (int it = 0; it < 64; ++it) {
        const int s = it & 15, buf = it & 1;
#pragma unroll
        for (int ii = 0; ii < 3; ++ii) {
            const int f = w * 3 + ii;
            const ushort* gp = &Whf[(size_t)(s * 24 + f) * 512 + l * 8];
            GLDS16(gp, &lds[buf][(8 + f) * 512]);
        }
        const float* p = xbase + s * 64;
        float4 u0 = *(const float4*)p;
        float4 u1 = *(const float4*)(p + 4);
        uint4 pk;
        pk.x = cvtpk(u0.x, u0.y); pk.y = cvtpk(u0.z, u0.w);
        pk.z = cvtpk(u1.x, u1.y); pk.w = cvtpk(u1.z, u1.w);
        *(uint4*)&lds[buf][s_slot] = pk;
        __syncthreads();
    }
    float cons = (float)lds[0][t * 8];
    asm volatile("" :: "v"(cons));
    if (g == 0 && t == 0) scratch[0] = cons;
}

// ---------------- PROBE B: compute phase only, amplified x4 ----------------
__global__ __launch_bounds__(512, 2) void k_probe_compute(float* __restrict__ scratch)
{
    __shared__ ushort lds[2][16384];
    const int t = threadIdx.x;
    const int w = t >> 6, l = t & 63;
    const int rw = w >> 2, cw = w & 3;
    // seed LDS (defeat undef-DCE); cheap
    for (int i = t; i < 16384; i += 512) {
        lds[0][i] = (ushort)(i * 2654435761u >> 16);
        lds[1][i] = (ushort)(i * 40503u >> 4);
    }
    __syncthreads();

    f32x4 acc[2][3];
#pragma unroll
    for (int j = 0; j < 2; ++j)
#pragma unroll
        for (int c = 0; c < 3; ++c) acc[j][c] = (f32x4){0.f, 0.f, 0.f, 0.f};

    for (int it = 0; it < 64; ++it) {
        const int buf = it & 1;
#pragma unroll
        for (int ks = 0; ks < 2; ++ks) {
            short8v a0 = *(const short8v*)&lds[buf][(((rw * 2 + 0) * 2 + ks) * 64 + l) * 8];
            short8v a1 = *(const short8v*)&lds[buf][(((rw * 2 + 1) * 2 + ks) * 64 + l) * 8];
#pragma unroll
            for (int c = 0; c < 3; ++c) {
                short8v b = *(const short8v*)&lds[buf][(8 + ((cw * 3 + c) * 2 + ks)) * 512 + l * 8];
                acc[0][c] = MFMA16(a0, b, acc[0][c], 0, 0, 0);
                acc[1][c] = MFMA16(a1, b, acc[1][c], 0, 0, 0);
            }
        }
        __syncthreads();
    }
#pragma unroll
    for (int j = 0; j < 2; ++j)
#pragma unroll
        for (int c = 0; c < 3; ++c)
#pragma unroll
            for (int q = 0; q < 4; ++q)
                asm volatile("" :: "v"(acc[j][c][q]));
    if (blockIdx.x == 0 && t == 0) scratch[0] = acc[0][0][0];
}

// ---------------- Kernel 2: per-chunk KV summary (MFMA, 1 wave/block) ----------------
__global__ __launch_bounds__(64) void k_chunksum(
    const ushort* __restrict__ KfT, const ushort* __restrict__ VT,
    float* __restrict__ KVc, float* __restrict__ Ksc)
{
    const int g = blockIdx.x, l = threadIdx.x;
    short8v ka[4][2], vb[4][2];
#pragma unroll
    for (int f = 0; f < 4; ++f)
#pragma unroll
        for (int js = 0; js < 2; ++js) {
            const size_t fo = ((size_t)(g * 8 + f * 2 + js)) * 512 + l * 8;
            ka[f][js] = *(const short8v*)&KfT[fo];
            vb[f][js] = *(const short8v*)&VT[fo];
        }
    short8v onesf;
#pragma unroll
    for (int e = 0; e < 8; ++e) onesf[e] = ((l & 15) == 0) ? (short)0x3F80 : (short)0;

    f32x4 acc[4][5];
#pragma unroll
    for (int kf = 0; kf < 4; ++kf)
#pragma unroll
        for (int mf = 0; mf < 5; ++mf) acc[kf][mf] = (f32x4){0.f, 0.f, 0.f, 0.f};
#pragma unroll
    for (int js = 0; js < 2; ++js)
#pragma unroll
        for (int kf = 0; kf < 4; ++kf) {
#pragma unroll
            for (int mf = 0; mf < 4; ++mf)
                acc[kf][mf] = MFMA16(ka[kf][js], vb[mf][js], acc[kf][mf], 0, 0, 0);
            acc[kf][4] = MFMA16(ka[kf][js], onesf, acc[kf][4], 0, 0, 0);
        }
    const int lq = l >> 4;
#pragma unroll
    for (int kf = 0; kf < 4; ++kf) {
#pragma unroll
        for (int q = 0; q < 4; ++q) {
            const int k = kf * 16 + lq * 4 + q;
#pragma unroll
            for (int mf = 0; mf < 4; ++mf)
                KVc[(size_t)g * 4096 + k * 64 + mf * 16 + (l & 15)] = acc[kf][mf][q];
            if ((l & 15) == 0) Ksc[(size_t)g * KDIM + k] = acc[kf][4][q];
        }
    }
}

// ---------------- Kernel 3: exclusive prefix over chunks (all-register) ----------------
__global__ void k_scan(const float* __restrict__ KVc, const float* __restrict__ Ksc,
                       float* __restrict__ Sst, float* __restrict__ Kss)
{
    const int b = blockIdx.x / 65;
    const int r = blockIdx.x % 65;
    const int t = threadIdx.x;
    if (r < 64) {
        const int e = r * 64 + t;
        float v[64];
#pragma unroll
        for (int i = 0; i < 64; ++i)
            v[i] = KVc[((size_t)(b * NCHUNK + i)) * 4096 + e];
        float acc = 0.f;
#pragma unroll
        for (int i = 0; i < 64; ++i) {
            Sst[((size_t)(b * NCHUNK + i)) * 4096 + e] = acc;
            acc += v[i];
        }
    } else {
        float v[64];
#pragma unroll
        for (int i = 0; i < 64; ++i)
            v[i] = Ksc[((size_t)(b * NCHUNK + i)) * KDIM + t];
        float acc = 0.f;
#pragma unroll
        for (int i = 0; i < 64; ++i) {
            Kss[((size_t)(b * NCHUNK + i)) * KDIM + t] = acc;
            acc += v[i];
        }
    }
}

// ---------------- Kernel 4: intra-chunk attention + output projection ----------------
__global__ __launch_bounds__(256) void k_intra(
    const ushort* __restrict__ Qf, const ushort* __restrict__ Kff,
    const ushort* __restrict__ VT, const float* __restrict__ Sst,
    const float* __restrict__ Kss, const ushort* __restrict__ Wof,
    float* __restrict__ out)
{
    __shared__ ushort pb[32 * 64];
    __shared__ ushort sT[80 * 64];
    __shared__ float ob[4][16 * 68 + 4];
    const int bx = blockIdx.x, t = threadIdx.x;
    const int g = bx >> 1, rh = bx & 1;
    const int w = t >> 6, l = t & 63;
    const int lq = l >> 4;

    {
        const int k = t >> 2, m0 = (t & 3) * 16;
        const float4* sp = (const float4*)&Sst[(size_t)g * 4096 + k * 64 + m0];
        float4 f0 = sp[0], f1 = sp[1], f2v = sp[2], f3 = sp[3];
        float fv[16] = {f0.x, f0.y, f0.z, f0.w, f1.x, f1.y, f1.z, f1.w,
                        f2v.x, f2v.y, f2v.z, f2v.w, f3.x, f3.y, f3.z, f3.w};
#pragma unroll
        for (int i = 0; i < 16; ++i) {
            const int m = m0 + i;
            sT[m * 64 + (k ^ ((m & 7) << 3))] = f2bf(fv[i]);
        }
        if (t < 64) sT[64 * 64 + t] = f2bf(Kss[(size_t)g * KDIM + t]);
        for (int idx = t; idx < 960; idx += 256) sT[65 * 64 + idx] = 0;
    }

    const int rf = w & 1;
    short8v qa[2];
#pragma unroll
    for (int ks = 0; ks < 2; ++ks)
        qa[ks] = *(const short8v*)&Qf[((size_t)((g * 2 + rh) * 4 + rf * 2 + ks)) * 512 + l * 8];
    {
        const int cfh = w >> 1;
        f32x4 accs[2];
#pragma unroll
        for (int ci = 0; ci < 2; ++ci) accs[ci] = (f32x4){0.f, 0.f, 0.f, 0.f};
#pragma unroll
        for (int ci = 0; ci < 2; ++ci) {
            const int cf = cfh * 2 + ci;
#pragma unroll
            for (int ks = 0; ks < 2; ++ks) {
                short8v kb = *(const short8v*)&Kff[((size_t)((g * 2 + (cf >> 1)) * 4 + (cf & 1) * 2 + ks)) * 512 + l * 8];
                accs[ci] = MFMA16(qa[ks], kb, accs[ci], 0, 0, 0);
            }
        }
#pragma unroll
        for (int ci = 0; ci < 2; ++ci)
#pragma unroll
            for (int q = 0; q < 4; ++q) {
                const int row = rf * 16 + lq * 4 + q;
                const int col = (cfh * 2 + ci) * 16 + (l & 15);
                const float sv = (col <= rh * 32 + row) ? accs[ci][q] : 0.f;
                pb[row * 64 + (col ^ ((row & 7) << 3))] = f2bf(sv);
            }
    }
    __syncthreads();

    const int mg = w >> 1;
    f32x4 an0 = (f32x4){0.f,0.f,0.f,0.f}, an1 = (f32x4){0.f,0.f,0.f,0.f};
    f32x4 ad = (f32x4){0.f,0.f,0.f,0.f};
    short8v onesf;
#pragma unroll
    for (int e = 0; e < 8; ++e) onesf[e] = ((l & 15) == 0) ? (short)0x3F80 : (short)0;
#pragma unroll
    for (int js = 0; js < 2; ++js) {
        const int prow = rf * 16 + (l & 15);
        const int pbase = js * 32 + ((l >> 4) & 3) * 8;
        short8v pa = *(const short8v*)&pb[prow * 64 + (pbase ^ ((prow & 7) << 3))];
        short8v v0 = *(const short8v*)&VT[((size_t)(g * 8 + (mg * 2 + 0) * 2 + js)) * 512 + l * 8];
        short8v v1 = *(const short8v*)&VT[((size_t)(g * 8 + (mg * 2 + 1) * 2 + js)) * 512 + l * 8];
        an0 = MFMA16(pa, v0, an0, 0, 0, 0);
        an1 = MFMA16(pa, v1, an1, 0, 0, 0);
        ad  = MFMA16(pa, onesf, ad, 0, 0, 0);
    }
#pragma unroll
    for (int ks = 0; ks < 2; ++ks) {
        const int base = ks * 32 + ((l >> 4) & 3) * 8;
        const int r0 = (mg * 2 + 0) * 16 + (l & 15);
        const int r1 = (mg * 2 + 1) * 16 + (l & 15);
        const int r4 = 64 + (l & 15);
        short8v s0 = *(const short8v*)&sT[r0 * 64 + (base ^ ((r0 & 7) << 3))];
        short8v s1 = *(const short8v*)&sT[r1 * 64 + (base ^ ((r1 & 7) << 3))];
        short8v s4 = *(const short8v*)&sT[r4 * 64 + (base ^ ((r4 & 7) << 3))];
        an0 = MFMA16(qa[ks], s0, an0, 0, 0, 0);
        an1 = MFMA16(qa[ks], s1, an1, 0, 0, 0);
        ad  = MFMA16(qa[ks], s4, ad, 0, 0, 0);
    }
#pragma unroll
    for (int q = 0; q < 4; ++q) {
        const float den = __shfl(ad[q], (l & 48));
        const float rinv = 1.f / (den + 1e-6f);
        const int row = rf * 16 + lq * 4 + q;
        const int c0 = (mg * 2 + 0) * 16 + (l & 15);
        const int c1 = (mg * 2 + 1) * 16 + (l & 15);
        pb[row * 64 + (c0 ^ ((row & 7) << 3))] = f2bf(an0[q] * rinv);
        pb[row * 64 + (c1 ^ ((row & 7) << 3))] = f2bf(an1[q] * rinv);
    }
    __syncthreads();

    short8v oa[2][2];
#pragma unroll
    for (int rfi = 0; rfi < 2; ++rfi)
#pragma unroll
        for (int ks = 0; ks < 2; ++ks) {
            const int row = rfi * 16 + (l & 15);
            const int base = ks * 32 + ((l >> 4) & 3) * 8;
            oa[rfi][ks] = *(const short8v*)&pb[row * 64 + (base ^ ((row & 7) << 3))];
        }
    float* obw = ob[w];
#pragma unroll
    for (int rr = 0; rr < 4; ++rr) {
        f32x4 acco[2][4];
#pragma unroll
        for (int rfi = 0; rfi < 2; ++rfi)
#pragma unroll
            for (int ci = 0; ci < 4; ++ci) acco[rfi][ci] = (f32x4){0.f, 0.f, 0.f, 0.f};
#pragma unroll
        for (int ci = 0; ci < 4; ++ci) {
            const int cfg = w * 16 + rr * 4 + ci;
#pragma unroll
            for (int ks = 0; ks < 2; ++ks) {
                short8v wb = *(const short8v*)&Wof[((size_t)(cfg * 2 + ks)) * 512 + l * 8];
#pragma unroll
                for (int rfi = 0; rfi < 2; ++rfi)
                    acco[rfi][ci] = MFMA16(oa[rfi][ks], wb, acco[rfi][ci], 0, 0, 0);
            }
        }
#pragma unroll
        for (int rfi = 0; rfi < 2; ++rfi) {
#pragma unroll
            for (int ci = 0; ci < 4; ++ci)
#pragma unroll
                for (int q = 0; q < 4; ++q)
                    obw[(lq * 4 + q) * 68 + ci * 16 + (l & 15)] = acco[rfi][ci][q];
#pragma unroll
            for (int rg = 0; rg < 4; ++rg) {
                const int row = rg * 4 + lq;
                float4 vv = *(const float4*)&obw[row * 68 + (l & 15) * 4];
                *(float4*)&out[((size_t)(g * 64 + rh * 32 + rfi * 16 + row)) * DDIM
                               + w * 256 + rr * 64 + (l & 15) * 4] = vv;
            }
        }
    }
}

extern "C" void kernel_launch(void* const* d_in, const int* in_sizes, int n_in,
                              void* d_out, int out_size, void* d_ws, size_t ws_size,
                              hipStream_t stream)
{
    const float* x  = (const float*)d_in[0];
    const float* Wq = (const float*)d_in[1];
    const float* Wk = (const float*)d_in[2];
    const float* Wv = (const float*)d_in[3];
    const float* Wo = (const float*)d_in[4];
    float* out = (float*)d_out;

    float* ws   = (float*)d_ws;
    float* KVc  = ws;                                  // 256*4096 f32
    float* Sst  = KVc + (size_t)TCHUNK * 4096;         // 256*4096 f32
    float* Ksc  = Sst + (size_t)TCHUNK * 4096;         // 256*64 f32
    float* Kss  = Ksc + (size_t)TCHUNK * KDIM;         // 256*64 f32
    ushort* Whf = (ushort*)(Kss + (size_t)TCHUNK * KDIM);  // 192*1024
    ushort* Wof = Whf + (size_t)192 * DDIM;                // 64*1024
    ushort* Qf  = Wof + (size_t)64 * 1024;                 // 512*4*512
    ushort* Kff = Qf  + (size_t)512 * 4 * 512;
    ushort* KfT = Kff + (size_t)512 * 4 * 512;             // 256*8*512
    ushort* VT  = KfT + (size_t)256 * 8 * 512;             // 256*8*512
    float* probeScratch = (float*)(VT + (size_t)256 * 8 * 512);

    k_wconv<<<dim3(256), dim3(256), 0, stream>>>(Wq, Wk, Wv, Wo, Whf, Wof);
    k_proj<<<dim3(TCHUNK), dim3(512), 0, stream>>>(x, Whf, Qf, Kff, KfT, VT);
    k_chunksum<<<dim3(TCHUNK), dim3(64), 0, stream>>>(KfT, VT, KVc, Ksc);
    k_scan<<<dim3(BB * 65), dim3(64), 0, stream>>>(KVc, Ksc, Sst, Kss);
    k_intra<<<dim3(TCHUNK * 2), dim3(256), 0, stream>>>(Qf, Kff, VT, Sst, Kss, Wof, out);
    // ---- diagnostic probes (write only to scratch; amplified x4 for top-5 visibility) ----
    k_probe_stage<<<dim3(TCHUNK), dim3(512), 0, stream>>>(x, Whf, probeScratch);
    k_probe_compute<<<dim3(TCHUNK), dim3(512), 0, stream>>>(probeScratch + 256);
}

// Round 13
// 52.007 us; speedup vs baseline: 2.8555x; 2.8555x over previous
//
#include <hip/hip_runtime.h>

#define BB 4
#define SS 4096
#define DDIM 1024
#define KDIM 64
#define NCHUNK 64          // SS / CHUNK
#define TCHUNK 256         // BB * NCHUNK
#define MROWS 16384        // BB * SS

typedef short short8v __attribute__((ext_vector_type(8)));
typedef float f32x4 __attribute__((ext_vector_type(4)));
#define MFMA16 __builtin_amdgcn_mfma_f32_16x16x32_bf16

#define GLDS16(gp, lp) __builtin_amdgcn_global_load_lds( \
    (const __attribute__((address_space(1))) unsigned int*)(gp), \
    (__attribute__((address_space(3))) unsigned int*)(lp), 16, 0, 0)

__device__ __forceinline__ ushort f2bf(float f) {
    uint u = __float_as_uint(f);
    u += 0x7FFFu + ((u >> 16) & 1u);
    return (ushort)(u >> 16);
}

__device__ __forceinline__ uint cvtpk(float lo, float hi) {
    uint r;
    asm("v_cvt_pk_bf16_f32 %0, %1, %2" : "=v"(r) : "v"(lo), "v"(hi));
    return r;
}

// ---------------- Kernel 0: weight conversion + fragment packing ----------------
__global__ __launch_bounds__(256) void k_wconv(
    const float* __restrict__ Wq, const float* __restrict__ Wk,
    const float* __restrict__ Wv, const float* __restrict__ Wo,
    ushort* __restrict__ Whf, ushort* __restrict__ Wof)
{
    const int b = blockIdx.x, t = threadIdx.x;
    const int ks = t >> 7;            // 0..1
    const int l = (t >> 1) & 63;      // lane
    const int half = t & 1;           // low/high 4 elems
    if (b < 192) {
        const int s = b / 12, cf = b % 12;
        const int grow = cf * 16 + (l & 15);
        const int gcol = s * 64 + ks * 32 + ((l >> 4) & 3) * 8 + half * 4;
        const float* src = (grow < 64) ? (Wq + (size_t)grow * DDIM)
                         : (grow < 128) ? (Wk + (size_t)(grow - 64) * DDIM)
                                        : (Wv + (size_t)(grow - 128) * DDIM);
        float4 v = *(const float4*)&src[gcol];
        ushort* dst = &Whf[(size_t)(((s * 12 + cf) * 2 + ks) * 64 + l) * 8 + half * 4];
        dst[0] = f2bf(v.x); dst[1] = f2bf(v.y); dst[2] = f2bf(v.z); dst[3] = f2bf(v.w);
    } else {
        const int cf = b - 192;           // 0..63
        const int d = cf * 16 + (l & 15);
        const int kc = ks * 32 + ((l >> 4) & 3) * 8 + half * 4;
        float4 v = *(const float4*)&Wo[(size_t)d * KDIM + kc];
        ushort* dst = &Wof[(size_t)((cf * 2 + ks) * 64 + l) * 8 + half * 4];
        dst[0] = f2bf(v.x); dst[1] = f2bf(v.y); dst[2] = f2bf(v.z); dst[3] = f2bf(v.w);
    }
}

// ---------------- Kernel 1: fused QKV projection v8 ----------------
// BM=32, grid 512 (2 blocks/CU), 512 thr = 8 waves (rw = w>>2 row-half, cw = w&3).
// Per step: A = x (one float4/thread, loaded TWO steps ahead in named regs,
// ds_write AFTER compute = T14), B = 24 W frags via shared global_load_lds.
// Double-buffered 2x28KB; one barrier per step.
#define EBP 216
__global__ __launch_bounds__(512, 2) void k_proj(
    const float* __restrict__ x, const ushort* __restrict__ Whf,
    ushort* __restrict__ Qf, ushort* __restrict__ Kff,
    ushort* __restrict__ KfT, ushort* __restrict__ VT)
{
    __shared__ ushort lds[2][14336];   // per buf: A 4x512 | B 24x512 (28 KB)
    const int t = threadIdx.x;
    const int w = t >> 6, l = t & 63;
    const int rw = w >> 2, cw = w & 3;
    const int mb = blockIdx.x;          // 0..511; chunk g = mb>>1, half rh = mb&1
    const int row0 = mb * 32;
    const int lq = l >> 4;

    // x geometry: thread t -> row r = t>>4 (0..31), cols c0 = (t&15)*4
    const int xr = t >> 4;
    const int xc = (t & 15) * 4;
    const float* xbase = &x[(size_t)(row0 + xr) * DDIM + xc];
    // A-frag slot: frag = (r>>4)*2 + (c>>5); lane = (r&15)|(((c>>3)&3)<<4); half = (c>>2)&1
    const int xslot = (((xr >> 4) * 2 + (xc >> 5)) * 64
                       + ((xr & 15) | (((xc >> 3) & 3) << 4))) * 8 + ((xc >> 2) & 1) * 4;

    auto ldX = [&](int s) -> float4 { return *(const float4*)(xbase + s * 64); };
    auto stX = [&](float4 v, int buf) {
        uint2 pk;
        pk.x = cvtpk(v.x, v.y);
        pk.y = cvtpk(v.z, v.w);
        *(uint2*)&lds[buf][xslot] = pk;
    };
    auto stageW = [&](int s, int buf) {
#pragma unroll
        for (int ii = 0; ii < 3; ++ii) {
            const int f = w * 3 + ii;
            const ushort* gp = &Whf[(size_t)(s * 24 + f) * 512 + l * 8];
            GLDS16(gp, &lds[buf][2048 + f * 512]);
        }
    };

    f32x4 acc[3];
#pragma unroll
    for (int c = 0; c < 3; ++c) acc[c] = (f32x4){0.f, 0.f, 0.f, 0.f};

    auto compute = [&](int buf) {
#pragma unroll
        for (int ks = 0; ks < 2; ++ks) {
            short8v a = *(const short8v*)&lds[buf][((rw * 2 + ks) * 64 + l) * 8];
#pragma unroll
            for (int c = 0; c < 3; ++c) {
                short8v b = *(const short8v*)&lds[buf][2048 + ((cw * 3 + c) * 2 + ks) * 512 + l * 8];
                acc[c] = MFMA16(a, b, acc[c], 0, 0, 0);
            }
        }
    };

    float4 xe = ldX(0);
    float4 xo = ldX(1);
    stageW(0, 0);
    stX(xe, 0);
    __syncthreads();
#pragma unroll
    for (int s2 = 0; s2 < 16; s2 += 2) {
        // even step s2 (buf0)
        if (s2 + 2 < 16) xe = ldX(s2 + 2);
        if (s2 + 1 < 16) stageW(s2 + 1, 1);
        compute(0);
        if (s2 + 1 < 16) stX(xo, 1);
        __syncthreads();
        // odd step s2+1 (buf1)
        if (s2 + 3 < 16) xo = ldX(s2 + 3);
        if (s2 + 2 < 16) stageW(s2 + 2, 0);
        if (s2 + 1 < 16) compute(1);
        if (s2 + 2 < 16) stX(xe, 0);
        __syncthreads();
    }

    // ---- epilogue: C-frags -> eb[32][EBP] (elu+1 on cols<128) ----
    ushort* eb = &lds[0][0];
#pragma unroll
    for (int c = 0; c < 3; ++c) {
        const int col = (cw * 3 + c) * 16 + (l & 15);
#pragma unroll
        for (int q = 0; q < 4; ++q) {
            const int row = rw * 16 + lq * 4 + q;
            float v = acc[c][q];
            if (col < 128) v = (v > 0.f) ? v + 1.f : __expf(v);  // elu+1
            eb[row * EBP + col] = f2bf(v);
        }
    }
    __syncthreads();

    // ---- Qf/Kff row-frag stores: 8 waves = (which, rf, ks) ----
    {
        const int which = w >> 2, rf = (w >> 1) & 1, ks = w & 1;
        const int r = rf * 16 + (l & 15);
        const int c0 = ks * 32 + ((l >> 4) & 3) * 8 + (which ? 64 : 0);
        short8v v8 = *(const short8v*)&eb[r * EBP + c0];
        const size_t fo = ((size_t)(mb * 4 + rf * 2 + ks)) * 512 + l * 8;
        if (which == 0) *(short8v*)&Qf[fo] = v8;
        else            *(short8v*)&Kff[fo] = v8;
    }
    // ---- KfT/VT T-frag stores: 8 waves = (which, f); js = mb&1 ----
    {
        const int which = w >> 2, f = w & 3;
        const int col = (which ? 128 : 64) + f * 16 + (l & 15);
        const int jb = ((l >> 4) & 3) * 8;
        short8v tv;
#pragma unroll
        for (int e = 0; e < 8; ++e) tv[e] = (short)eb[(jb + e) * EBP + col];
        const size_t fo = ((size_t)((mb >> 1) * 8 + f * 2 + (mb & 1))) * 512 + l * 8;
        if (which == 0) *(short8v*)&KfT[fo] = tv;
        else            *(short8v*)&VT[fo]  = tv;
    }
}

// ---------------- Kernel 2: per-chunk KV summary (MFMA, 1 wave/block) ----------------
__global__ __launch_bounds__(64) void k_chunksum(
    const ushort* __restrict__ KfT, const ushort* __restrict__ VT,
    float* __restrict__ KVc, float* __restrict__ Ksc)
{
    const int g = blockIdx.x, l = threadIdx.x;
    short8v ka[4][2], vb[4][2];
#pragma unroll
    for (int f = 0; f < 4; ++f)
#pragma unroll
        for (int js = 0; js < 2; ++js) {
            const size_t fo = ((size_t)(g * 8 + f * 2 + js)) * 512 + l * 8;
            ka[f][js] = *(const short8v*)&KfT[fo];
            vb[f][js] = *(const short8v*)&VT[fo];
        }
    short8v onesf;
#pragma unroll
    for (int e = 0; e < 8; ++e) onesf[e] = ((l & 15) == 0) ? (short)0x3F80 : (short)0;

    f32x4 acc[4][5];
#pragma unroll
    for (int kf = 0; kf < 4; ++kf)
#pragma unroll
        for (int mf = 0; mf < 5; ++mf) acc[kf][mf] = (f32x4){0.f, 0.f, 0.f, 0.f};
#pragma unroll
    for (int js = 0; js < 2; ++js)
#pragma unroll
        for (int kf = 0; kf < 4; ++kf) {
#pragma unroll
            for (int mf = 0; mf < 4; ++mf)
                acc[kf][mf] = MFMA16(ka[kf][js], vb[mf][js], acc[kf][mf], 0, 0, 0);
            acc[kf][4] = MFMA16(ka[kf][js], onesf, acc[kf][4], 0, 0, 0);
        }
    const int lq = l >> 4;
#pragma unroll
    for (int kf = 0; kf < 4; ++kf) {
#pragma unroll
        for (int q = 0; q < 4; ++q) {
            const int k = kf * 16 + lq * 4 + q;
#pragma unroll
            for (int mf = 0; mf < 4; ++mf)
                KVc[(size_t)g * 4096 + k * 64 + mf * 16 + (l & 15)] = acc[kf][mf][q];
            if ((l & 15) == 0) Ksc[(size_t)g * KDIM + k] = acc[kf][4][q];
        }
    }
}

// ---------------- Kernel 3: exclusive prefix over chunks (all-register) ----------------
__global__ void k_scan(const float* __restrict__ KVc, const float* __restrict__ Ksc,
                       float* __restrict__ Sst, float* __restrict__ Kss)
{
    const int b = blockIdx.x / 65;
    const int r = blockIdx.x % 65;
    const int t = threadIdx.x;
    if (r < 64) {
        const int e = r * 64 + t;
        float v[64];
#pragma unroll
        for (int i = 0; i < 64; ++i)
            v[i] = KVc[((size_t)(b * NCHUNK + i)) * 4096 + e];
        float acc = 0.f;
#pragma unroll
        for (int i = 0; i < 64; ++i) {
            Sst[((size_t)(b * NCHUNK + i)) * 4096 + e] = acc;
            acc += v[i];
        }
    } else {
        float v[64];
#pragma unroll
        for (int i = 0; i < 64; ++i)
            v[i] = Ksc[((size_t)(b * NCHUNK + i)) * KDIM + t];
        float acc = 0.f;
#pragma unroll
        for (int i = 0; i < 64; ++i) {
            Kss[((size_t)(b * NCHUNK + i)) * KDIM + t] = acc;
            acc += v[i];
        }
    }
}

// ---------------- Kernel 4: intra-chunk attention + output projection ----------------
__global__ __launch_bounds__(256) void k_intra(
    const ushort* __restrict__ Qf, const ushort* __restrict__ Kff,
    const ushort* __restrict__ VT, const float* __restrict__ Sst,
    const float* __restrict__ Kss, const ushort* __restrict__ Wof,
    float* __restrict__ out)
{
    __shared__ ushort pb[32 * 64];
    __shared__ ushort sT[80 * 64];
    __shared__ float ob[4][16 * 68 + 4];
    const int bx = blockIdx.x, t = threadIdx.x;
    const int g = bx >> 1, rh = bx & 1;
    const int w = t >> 6, l = t & 63;
    const int lq = l >> 4;

    {
        const int k = t >> 2, m0 = (t & 3) * 16;
        const float4* sp = (const float4*)&Sst[(size_t)g * 4096 + k * 64 + m0];
        float4 f0 = sp[0], f1 = sp[1], f2v = sp[2], f3 = sp[3];
        float fv[16] = {f0.x, f0.y, f0.z, f0.w, f1.x, f1.y, f1.z, f1.w,
                        f2v.x, f2v.y, f2v.z, f2v.w, f3.x, f3.y, f3.z, f3.w};
#pragma unroll
        for (int i = 0; i < 16; ++i) {
            const int m = m0 + i;
            sT[m * 64 + (k ^ ((m & 7) << 3))] = f2bf(fv[i]);
        }
        if (t < 64) sT[64 * 64 + t] = f2bf(Kss[(size_t)g * KDIM + t]);
        for (int idx = t; idx < 960; idx += 256) sT[65 * 64 + idx] = 0;
    }

    const int rf = w & 1;
    short8v qa[2];
#pragma unroll
    for (int ks = 0; ks < 2; ++ks)
        qa[ks] = *(const short8v*)&Qf[((size_t)((g * 2 + rh) * 4 + rf * 2 + ks)) * 512 + l * 8];
    {
        const int cfh = w >> 1;
        f32x4 accs[2];
#pragma unroll
        for (int ci = 0; ci < 2; ++ci) accs[ci] = (f32x4){0.f, 0.f, 0.f, 0.f};
#pragma unroll
        for (int ci = 0; ci < 2; ++ci) {
            const int cf = cfh * 2 + ci;
#pragma unroll
            for (int ks = 0; ks < 2; ++ks) {
                short8v kb = *(const short8v*)&Kff[((size_t)((g * 2 + (cf >> 1)) * 4 + (cf & 1) * 2 + ks)) * 512 + l * 8];
                accs[ci] = MFMA16(qa[ks], kb, accs[ci], 0, 0, 0);
            }
        }
#pragma unroll
        for (int ci = 0; ci < 2; ++ci)
#pragma unroll
            for (int q = 0; q < 4; ++q) {
                const int row = rf * 16 + lq * 4 + q;
                const int col = (cfh * 2 + ci) * 16 + (l & 15);
                const float sv = (col <= rh * 32 + row) ? accs[ci][q] : 0.f;
                pb[row * 64 + (col ^ ((row & 7) << 3))] = f2bf(sv);
            }
    }
    __syncthreads();

    const int mg = w >> 1;
    f32x4 an0 = (f32x4){0.f,0.f,0.f,0.f}, an1 = (f32x4){0.f,0.f,0.f,0.f};
    f32x4 ad = (f32x4){0.f,0.f,0.f,0.f};
    short8v onesf;
#pragma unroll
    for (int e = 0; e < 8; ++e) onesf[e] = ((l & 15) == 0) ? (short)0x3F80 : (short)0;
#pragma unroll
    for (int js = 0; js < 2; ++js) {
        const int prow = rf * 16 + (l & 15);
        const int pbase = js * 32 + ((l >> 4) & 3) * 8;
        short8v pa = *(const short8v*)&pb[prow * 64 + (pbase ^ ((prow & 7) << 3))];
        short8v v0 = *(const short8v*)&VT[((size_t)(g * 8 + (mg * 2 + 0) * 2 + js)) * 512 + l * 8];
        short8v v1 = *(const short8v*)&VT[((size_t)(g * 8 + (mg * 2 + 1) * 2 + js)) * 512 + l * 8];
        an0 = MFMA16(pa, v0, an0, 0, 0, 0);
        an1 = MFMA16(pa, v1, an1, 0, 0, 0);
        ad  = MFMA16(pa, onesf, ad, 0, 0, 0);
    }
#pragma unroll
    for (int ks = 0; ks < 2; ++ks) {
        const int base = ks * 32 + ((l >> 4) & 3) * 8;
        const int r0 = (mg * 2 + 0) * 16 + (l & 15);
        const int r1 = (mg * 2 + 1) * 16 + (l & 15);
        const int r4 = 64 + (l & 15);
        short8v s0 = *(const short8v*)&sT[r0 * 64 + (base ^ ((r0 & 7) << 3))];
        short8v s1 = *(const short8v*)&sT[r1 * 64 + (base ^ ((r1 & 7) << 3))];
        short8v s4 = *(const short8v*)&sT[r4 * 64 + (base ^ ((r4 & 7) << 3))];
        an0 = MFMA16(qa[ks], s0, an0, 0, 0, 0);
        an1 = MFMA16(qa[ks], s1, an1, 0, 0, 0);
        ad  = MFMA16(qa[ks], s4, ad, 0, 0, 0);
    }
#pragma unroll
    for (int q = 0; q < 4; ++q) {
        const float den = __shfl(ad[q], (l & 48));
        const float rinv = 1.f / (den + 1e-6f);
        const int row = rf * 16 + lq * 4 + q;
        const int c0 = (mg * 2 + 0) * 16 + (l & 15);
        const int c1 = (mg * 2 + 1) * 16 + (l & 15);
        pb[row * 64 + (c0 ^ ((row & 7) << 3))] = f2bf(an0[q] * rinv);
        pb[row * 64 + (c1 ^ ((row & 7) << 3))] = f2bf(an1[q] * rinv);
    }
    __syncthreads();

    short8v oa[2][2];
#pragma unroll
    for (int rfi = 0; rfi < 2; ++rfi)
#pragma unroll
        for (int ks = 0; ks < 2; ++ks) {
            const int row = rfi * 16 + (l & 15);
            const int base = ks * 32 + ((l >> 4) & 3) * 8;
            oa[rfi][ks] = *(const short8v*)&pb[row * 64 + (base ^ ((row & 7) << 3))];
        }
    float* obw = ob[w];
#pragma unroll
    for (int rr = 0; rr < 4; ++rr) {
        f32x4 acco[2][4];
#pragma unroll
        for (int rfi = 0; rfi < 2; ++rfi)
#pragma unroll
            for (int ci = 0; ci < 4; ++ci) acco[rfi][ci] = (f32x4){0.f, 0.f, 0.f, 0.f};
#pragma unroll
        for (int ci = 0; ci < 4; ++ci) {
            const int cfg = w * 16 + rr * 4 + ci;
#pragma unroll
            for (int ks = 0; ks < 2; ++ks) {
                short8v wb = *(const short8v*)&Wof[((size_t)(cfg * 2 + ks)) * 512 + l * 8];
#pragma unroll
                for (int rfi = 0; rfi < 2; ++rfi)
                    acco[rfi][ci] = MFMA16(oa[rfi][ks], wb, acco[rfi][ci], 0, 0, 0);
            }
        }
#pragma unroll
        for (int rfi = 0; rfi < 2; ++rfi) {
#pragma unroll
            for (int ci = 0; ci < 4; ++ci)
#pragma unroll
                for (int q = 0; q < 4; ++q)
                    obw[(lq * 4 + q) * 68 + ci * 16 + (l & 15)] = acco[rfi][ci][q];
#pragma unroll
            for (int rg = 0; rg < 4; ++rg) {
                const int row = rg * 4 + lq;
                float4 vv = *(const float4*)&obw[row * 68 + (l & 15) * 4];
                *(float4*)&out[((size_t)(g * 64 + rh * 32 + rfi * 16 + row)) * DDIM
                               + w * 256 + rr * 64 + (l & 15) * 4] = vv;
            }
        }
    }
}

extern "C" void kernel_launch(void* const* d_in, const int* in_sizes, int n_in,
                              void* d_out, int out_size, void* d_ws, size_t ws_size,
                              hipStream_t stream)
{
    const float* x  = (const float*)d_in[0];
    const float* Wq = (const float*)d_in[1];
    const float* Wk = (const float*)d_in[2];
    const float* Wv = (const float*)d_in[3];
    const float* Wo = (const float*)d_in[4];
    float* out = (float*)d_out;

    float* ws   = (float*)d_ws;
    float* KVc  = ws;                                  // 256*4096 f32
    float* Sst  = KVc + (size_t)TCHUNK * 4096;         // 256*4096 f32
    float* Ksc  = Sst + (size_t)TCHUNK * 4096;         // 256*64 f32
    float* Kss  = Ksc + (size_t)TCHUNK * KDIM;         // 256*64 f32
    ushort* Whf = (ushort*)(Kss + (size_t)TCHUNK * KDIM);  // 192*1024
    ushort* Wof = Whf + (size_t)192 * DDIM;                // 64*1024
    ushort* Qf  = Wof + (size_t)64 * 1024;                 // 512*4*512
    ushort* Kff = Qf  + (size_t)512 * 4 * 512;
    ushort* KfT = Kff + (size_t)512 * 4 * 512;             // 256*8*512
    ushort* VT  = KfT + (size_t)256 * 8 * 512;             // 256*8*512

    k_wconv<<<dim3(256), dim3(256), 0, stream>>>(Wq, Wk, Wv, Wo, Whf, Wof);
    k_proj<<<dim3(MROWS / 32), dim3(512), 0, stream>>>(x, Whf, Qf, Kff, KfT, VT);
    k_chunksum<<<dim3(TCHUNK), dim3(64), 0, stream>>>(KfT, VT, KVc, Ksc);
    k_scan<<<dim3(BB * 65), dim3(64), 0, stream>>>(KVc, Ksc, Sst, Kss);
    k_intra<<<dim3(TCHUNK * 2), dim3(256), 0, stream>>>(Qf, Kff, VT, Sst, Kss, Wof, out);
}